// Round 5
// baseline (134.130 us; speedup 1.0000x reference)
//
#include <hip/hip_runtime.h>
#include <math.h>

#define HN 8
#define HH 512
#define HW 512
#define NPIX (HH*HW)        // 262144 per image
#define NTOT (HN*NPIX)      // 2097152 total
#define INF1D 1.0e6f
#define BIGF 3.0e38f
#define SQINF 4.4e9f        // > 65535^2, acts as +inf for squared distances

// ---------------------------------------------------------------------------
// Kernel A: per-row 1D distance (along W) for both feature sets, packed u16x2.
// low16 = dist_in (EDT of ~m), high16 = dist_out (EDT of m).
// One wave per row; each lane owns 8 consecutive pixels.
// ---------------------------------------------------------------------------
__global__ __launch_bounds__(256) void k_rows(const float* __restrict__ gt,
                                              unsigned int* __restrict__ packed) {
  const int lane = threadIdx.x & 63;
  const int wv   = threadIdx.x >> 6;
  const int row  = blockIdx.x * 4 + wv;          // 0..4095 = n*512 + h
  const float* g = gt + (size_t)row * HW;

  float4 a0 = *(const float4*)(g + lane * 8);
  float4 a1 = *(const float4*)(g + lane * 8 + 4);
  float mv[8] = {a0.x, a0.y, a0.z, a0.w, a1.x, a1.y, a1.z, a1.w};

  float pin[8], pout[8], sfin[8], sfout[8];
  float rin = BIGF, rout = BIGF;
  for (int j = 0; j < 8; ++j) {
    float wf = (float)(lane * 8 + j);
    bool m = mv[j] > 0.5f;
    float gin  = m ? INF1D : 0.f;   // feature_in  = ~m
    float gout = m ? 0.f : INF1D;   // feature_out =  m
    rin  = fminf(rin,  gin  - wf);  pin[j]  = rin;
    rout = fminf(rout, gout - wf);  pout[j] = rout;
  }
  // exclusive wave prefix-min of lane totals
  float xin = rin, xout = rout;
  for (int off = 1; off < 64; off <<= 1) {
    float yi = __shfl_up(xin, off);
    float yo = __shfl_up(xout, off);
    if (lane >= off) { xin = fminf(xin, yi); xout = fminf(xout, yo); }
  }
  float ein  = __shfl_up(xin, 1);  if (lane == 0) ein  = BIGF;
  float eout = __shfl_up(xout, 1); if (lane == 0) eout = BIGF;

  float rsin = BIGF, rsout = BIGF;
  for (int j = 7; j >= 0; --j) {
    float wf = (float)(lane * 8 + j);
    bool m = mv[j] > 0.5f;
    float gin  = m ? INF1D : 0.f;
    float gout = m ? 0.f : INF1D;
    rsin  = fminf(rsin,  gin  + wf);  sfin[j]  = rsin;
    rsout = fminf(rsout, gout + wf);  sfout[j] = rsout;
  }
  float zin = rsin, zout = rsout;
  for (int off = 1; off < 64; off <<= 1) {
    float yi = __shfl_down(zin, off);
    float yo = __shfl_down(zout, off);
    if (lane + off < 64) { zin = fminf(zin, yi); zout = fminf(zout, yo); }
  }
  float sein  = __shfl_down(zin, 1);  if (lane == 63) sein  = BIGF;
  float seout = __shfl_down(zout, 1); if (lane == 63) seout = BIGF;

  unsigned int outp[8];
  for (int j = 0; j < 8; ++j) {
    float wf = (float)(lane * 8 + j);
    float fin  = wf + fminf(pin[j],  ein);
    float fout = wf + fminf(pout[j], eout);
    float bin  = fminf(sfin[j],  sein)  - wf;
    float bout = fminf(sfout[j], seout) - wf;
    float g1i = fminf(fin,  bin);
    float g1o = fminf(fout, bout);
    unsigned int di = (g1i > 65534.f) ? 0xFFFFu : (unsigned int)(g1i + 0.5f);
    unsigned int dq = (g1o > 65534.f) ? 0xFFFFu : (unsigned int)(g1o + 0.5f);
    outp[j] = di | (dq << 16);
  }
  unsigned int* dst = packed + (size_t)row * HW + lane * 8;
  *(uint4*)dst       = make_uint4(outp[0], outp[1], outp[2], outp[3]);
  *(uint4*)(dst + 4) = make_uint4(outp[4], outp[5], outp[6], outp[7]);
}

// ---------------------------------------------------------------------------
// Kernel B: column pass. Block = 64 cols x 32 output rows; window +-32 halo.
// LDS holds PRE-SQUARED f32 distances in two class planes (sq_in / sq_out) so
// the scan needs no extraction VALU. Each thread's 8 pixels share one column:
// a 24-row register sliding window covers all dk<=8 for all 8 pixels
// (48 LDS reads/thread instead of 136). Guarded exact tail for dk>=9.
// Per-wave max written to partials (no atomics).
// ---------------------------------------------------------------------------
#define ICH 32
#define HALO 32
__global__ __launch_bounds__(256) void k_cols(const unsigned int* __restrict__ packed,
                                              float* __restrict__ sd,
                                              float* __restrict__ partials) {
  __shared__ float sq[2][96][64];         // 48 KB: [0]=in (low16), [1]=out (high16)
  const int tid = threadIdx.x;
  const int wx = blockIdx.x;              // 0..7  w-tile
  const int iy = blockIdx.y;              // 0..15 i-chunk
  const int n  = blockIdx.z;
  const int I0 = iy * ICH;
  const int kb = max(0, I0 - HALO);
  const int ke = min(HH, I0 + ICH + HALO);
  const int sz = ke - kb;
  const int w0 = wx * 64;
  const unsigned int* src = packed + (size_t)n * NPIX + (size_t)kb * HW + w0;

  // stage: sz rows x 64 cols; uint4 load -> two float4 LDS writes (squared)
  const int total4 = sz * 16;
  for (int p4 = tid; p4 < total4; p4 += 256) {
    int row = p4 >> 4;
    int c4  = (p4 & 15) << 2;
    uint4 v = *(const uint4*)(src + (size_t)row * HW + c4);
    unsigned int u[4] = {v.x, v.y, v.z, v.w};
    float fi[4], fo[4];
#pragma unroll
    for (int e = 0; e < 4; ++e) {
      unsigned int di = u[e] & 0xFFFFu;
      unsigned int dq = u[e] >> 16;
      fi[e] = (float)(di * di);
      fo[e] = (float)(dq * dq);
    }
    *(float4*)&sq[0][row][c4] = make_float4(fi[0], fi[1], fi[2], fi[3]);
    *(float4*)&sq[1][row][c4] = make_float4(fo[0], fo[1], fo[2], fo[3]);
  }
  __syncthreads();

  const int lane = tid & 63;
  const int wv   = tid >> 6;
  const int col  = lane;
  const int base = I0 - kb + wv * 8;      // window row of this thread's q=0 pixel

  // register sliding window: rows [base-8, base+15], both classes
  float rin[24], rout[24];
#pragma unroll
  for (int t = 0; t < 24; ++t) {
    int rw = base - 8 + t;
    bool ok = (rw >= 0) && (rw < sz);
    int rc = min(max(rw, 0), sz - 1);
    float a = sq[0][rc][col];
    float b = sq[1][rc][col];
    rin[t]  = ok ? a : SQINF;
    rout[t] = ok ? b : SQINF;
  }

  float lmax = -BIGF;
#pragma unroll
  for (int q = 0; q < 8; ++q) {
    const bool m = (rout[q + 8] == 0.f);  // inside <=> dist_out == 0
    float best = m ? rin[q + 8] : rout[q + 8];
#pragma unroll
    for (int dk = 1; dk <= 8; ++dk) {
      const float dkk = (float)(dk * dk);
      float a = m ? rin[q + 8 - dk] : rout[q + 8 - dk];
      float b = m ? rin[q + 8 + dk] : rout[q + 8 + dk];
      best = fminf(best, a + dkk);
      best = fminf(best, b + dkk);
    }
    // exact guarded tail (rare: needs a pixel with 1D distance > 8)
    const int li = base + q;
    const int cls = m ? 0 : 1;
    for (int dk = 9; dk < 96; ++dk) {
      float dkk = (float)(dk * dk);
      if (__all(dkk >= best)) break;
      int k1 = li - dk, k2 = li + dk;
      float a = (k1 >= 0) ? sq[cls][k1][col] : SQINF;
      float b = (k2 < sz) ? sq[cls][k2][col] : SQINF;
      best = fminf(best, a + dkk);
      best = fminf(best, b + dkk);
    }
    const int i = I0 + wv * 8 + q;
    float s = m ? sqrtf(best) : -sqrtf(best);
    sd[(size_t)n * NPIX + (size_t)i * HW + w0 + col] = s;
    lmax = fmaxf(lmax, s);
  }
  for (int off = 32; off; off >>= 1) lmax = fmaxf(lmax, __shfl_xor(lmax, off));
  if (lane == 0) partials[((n * 16 + iy) * 8 + wx) * 4 + wv] = lmax;
}

// ---------------------------------------------------------------------------
// Kernel C: fused loss. Each block first reduces its image's 512 k_cols wave
// maxes (2 KB, L2) to get wsmax inline — no separate k_rmax kernel. Then the
// elementwise terms (8 px/thread, 10 independent float4 loads, __logf), block
// partials stored to private slots (no contended atomics).
// ---------------------------------------------------------------------------
__global__ __launch_bounds__(256) void k_loss(const float* __restrict__ seg_p,
                                              const float* __restrict__ seg_t,
                                              const float* __restrict__ edge_p,
                                              const float* __restrict__ edge_t,
                                              const float* __restrict__ sd,
                                              const float* __restrict__ partials,
                                              float* __restrict__ partials2) {
  const int n = blockIdx.x >> 7;
  const int tid = threadIdx.x;
  const int wv = tid >> 6, ln = tid & 63;

  // inline wsmax reduce
  const float* pmx = partials + n * 512;
  float v = fmaxf(pmx[tid], pmx[tid + 256]);
  for (int off = 32; off; off >>= 1) v = fmaxf(v, __shfl_xor(v, off));
  __shared__ float smax[4];
  if (ln == 0) smax[wv] = v;
  __syncthreads();
  const float mx = fmaxf(fmaxf(smax[0], smax[1]), fmaxf(smax[2], smax[3]));
  const float inv = (mx > 0.f) ? 1.f / (mx + 1e-6f) : 1.f;
  const float HI = 1.0f - 1e-7f;

  const size_t base = (size_t)n * NPIX + (size_t)(blockIdx.x & 127) * 2048
                    + (size_t)tid * 8;

  float a_bce = 0.f, a_pt = 0.f, a_ps = 0.f, a_ts = 0.f, a_ed = 0.f, a_bd = 0.f;
  for (int h = 0; h < 8; h += 4) {
    float4 p4  = *(const float4*)(seg_p  + base + h);
    float4 t4  = *(const float4*)(seg_t  + base + h);
    float4 ep4 = *(const float4*)(edge_p + base + h);
    float4 et4 = *(const float4*)(edge_t + base + h);
    float4 s4  = *(const float4*)(sd     + base + h);
    float pa[4]  = {p4.x, p4.y, p4.z, p4.w};
    float ta[4]  = {t4.x, t4.y, t4.z, t4.w};
    float epa[4] = {ep4.x, ep4.y, ep4.z, ep4.w};
    float eta[4] = {et4.x, et4.y, et4.z, et4.w};
    float sa[4]  = {s4.x, s4.y, s4.z, s4.w};
#pragma unroll
    for (int j = 0; j < 4; ++j) {
      float p = pa[j], t = ta[j];
      float pc = fminf(fmaxf(p, 1e-7f), HI);
      a_bce += -(t * __logf(pc) + (1.f - t) * __logf(1.f - pc));
      a_pt  += p * t;
      a_ps  += p;
      a_ts  += t;
      float ep = epa[j], et = eta[j];
      float ec = fminf(fmaxf(ep, 1e-7f), HI);
      float el = -(et * __logf(ec) + (1.f - et) * __logf(1.f - ec));
      a_ed += el * (et > 0.5f ? 0.9f : 0.1f);
      float sn = sa[j] * inv;
      sn = fminf(fmaxf(sn, -1.f), 1.f);
      a_bd += fabsf(p - t) * fabsf(sn);
    }
  }
  for (int off = 32; off; off >>= 1) {
    a_bce += __shfl_xor(a_bce, off);
    a_pt  += __shfl_xor(a_pt,  off);
    a_ps  += __shfl_xor(a_ps,  off);
    a_ts  += __shfl_xor(a_ts,  off);
    a_ed  += __shfl_xor(a_ed,  off);
    a_bd  += __shfl_xor(a_bd,  off);
  }
  __shared__ float red[4][6];
  if (ln == 0) {
    red[wv][0] = a_bce; red[wv][1] = a_pt; red[wv][2] = a_ps;
    red[wv][3] = a_ts;  red[wv][4] = a_ed; red[wv][5] = a_bd;
  }
  __syncthreads();
  if (tid == 0) {
    float* dst = partials2 + (size_t)blockIdx.x * 8;
    dst[0] = red[0][0] + red[1][0] + red[2][0] + red[3][0];
    dst[1] = red[0][1] + red[1][1] + red[2][1] + red[3][1];
    dst[2] = red[0][2] + red[1][2] + red[2][2] + red[3][2];
    dst[3] = red[0][3] + red[1][3] + red[2][3] + red[3][3];
    dst[4] = red[0][4] + red[1][4] + red[2][4] + red[3][4];
    dst[5] = red[0][5] + red[1][5] + red[2][5] + red[3][5];
  }
}

// ---------------------------------------------------------------------------
// Kernel D: final reduce of 1024 block-partials (32 KB, L2-resident) + scalar.
// ---------------------------------------------------------------------------
__global__ __launch_bounds__(256) void k_final(const float* __restrict__ partials2,
                                               float* __restrict__ out) {
  const int t = threadIdx.x;
  const int n = t >> 5;        // image 0..7
  const int l = t & 31;
  float s0 = 0.f, s1 = 0.f, s2 = 0.f, s3 = 0.f, s4 = 0.f, s5 = 0.f;
#pragma unroll
  for (int it = 0; it < 4; ++it) {
    const float* p = partials2 + (size_t)((n * 128) + l + it * 32) * 8;
    s0 += p[0]; s1 += p[1]; s2 += p[2];
    s3 += p[3]; s4 += p[4]; s5 += p[5];
  }
  for (int off = 16; off; off >>= 1) {
    s0 += __shfl_xor(s0, off); s1 += __shfl_xor(s1, off);
    s2 += __shfl_xor(s2, off); s3 += __shfl_xor(s3, off);
    s4 += __shfl_xor(s4, off); s5 += __shfl_xor(s5, off);
  }
  __shared__ float red[8][6];
  if (l == 0) {
    red[n][0] = s0; red[n][1] = s1; red[n][2] = s2;
    red[n][3] = s3; red[n][4] = s4; red[n][5] = s5;
  }
  __syncthreads();
  if (t == 0) {
    const float M = (float)NTOT;
    float bce = 0.f, ed = 0.f, bd = 0.f, dsum = 0.f;
    for (int nn = 0; nn < HN; ++nn) {
      bce += red[nn][0]; ed += red[nn][4]; bd += red[nn][5];
      float den = red[nn][2] + red[nn][3] + 1e-6f;
      dsum += 2.f * red[nn][1] / den;
    }
    float dice = 1.f - dsum / (float)HN;
    out[0] = bce / M + 0.5f * dice + 0.5f * (ed / M) + 0.2f * (bd / M);
  }
}

extern "C" void kernel_launch(void* const* d_in, const int* in_sizes, int n_in,
                              void* d_out, int out_size, void* d_ws, size_t ws_size,
                              hipStream_t stream) {
  const float* seg_p  = (const float*)d_in[0];
  const float* seg_t  = (const float*)d_in[1];
  const float* edge_p = (const float*)d_in[2];
  const float* edge_t = (const float*)d_in[3];
  float* out = (float*)d_out;

  char* ws = (char*)d_ws;
  unsigned int* packed = (unsigned int*)ws;                    // 8 MB: u16x2 row dists
  float* sd        = (float*)(ws + (size_t)NTOT * 4);          // 8 MB: signed distance
  float* partials  = (float*)(ws + (size_t)NTOT * 8);          // 8*512 floats (k_cols wave maxes)
  float* partials2 = partials + 8 * 512;                       // 1024*8 floats (k_loss partials)

  k_rows<<<dim3(HN * HH / 4), 256, 0, stream>>>(seg_t, packed);
  k_cols<<<dim3(8, 16, HN), 256, 0, stream>>>(packed, sd, partials);
  k_loss<<<dim3(HN * 128), 256, 0, stream>>>(seg_p, seg_t, edge_p, edge_t, sd, partials, partials2);
  k_final<<<1, 256, 0, stream>>>(partials2, out);
}

// Round 6
// 103.260 us; speedup vs baseline: 1.2990x; 1.2990x over previous
//
#include <hip/hip_runtime.h>
#include <math.h>

#define HN 8
#define HH 512
#define HW 512
#define NPIX (HH*HW)        // 262144 per image
#define NTOT (HN*NPIX)      // 2097152 total
#define INF1D 1.0e6f
#define BIGF 3.0e38f
#define SQINF 4.4e9f        // > 65535^2, acts as +inf for squared distances

// ---------------------------------------------------------------------------
// Kernel A: per-row 1D distance (along W) for both feature sets, packed u16x2.
// low16 = dist_in (EDT of ~m), high16 = dist_out (EDT of m).
// One wave per row; each lane owns 8 consecutive pixels.
// ---------------------------------------------------------------------------
__global__ __launch_bounds__(256) void k_rows(const float* __restrict__ gt,
                                              unsigned int* __restrict__ packed) {
  const int lane = threadIdx.x & 63;
  const int wv   = threadIdx.x >> 6;
  const int row  = blockIdx.x * 4 + wv;          // 0..4095 = n*512 + h
  const float* g = gt + (size_t)row * HW;

  float4 a0 = *(const float4*)(g + lane * 8);
  float4 a1 = *(const float4*)(g + lane * 8 + 4);
  float mv[8] = {a0.x, a0.y, a0.z, a0.w, a1.x, a1.y, a1.z, a1.w};

  float pin[8], pout[8], sfin[8], sfout[8];
  float rin = BIGF, rout = BIGF;
  for (int j = 0; j < 8; ++j) {
    float wf = (float)(lane * 8 + j);
    bool m = mv[j] > 0.5f;
    float gin  = m ? INF1D : 0.f;   // feature_in  = ~m
    float gout = m ? 0.f : INF1D;   // feature_out =  m
    rin  = fminf(rin,  gin  - wf);  pin[j]  = rin;
    rout = fminf(rout, gout - wf);  pout[j] = rout;
  }
  // exclusive wave prefix-min of lane totals
  float xin = rin, xout = rout;
  for (int off = 1; off < 64; off <<= 1) {
    float yi = __shfl_up(xin, off);
    float yo = __shfl_up(xout, off);
    if (lane >= off) { xin = fminf(xin, yi); xout = fminf(xout, yo); }
  }
  float ein  = __shfl_up(xin, 1);  if (lane == 0) ein  = BIGF;
  float eout = __shfl_up(xout, 1); if (lane == 0) eout = BIGF;

  float rsin = BIGF, rsout = BIGF;
  for (int j = 7; j >= 0; --j) {
    float wf = (float)(lane * 8 + j);
    bool m = mv[j] > 0.5f;
    float gin  = m ? INF1D : 0.f;
    float gout = m ? 0.f : INF1D;
    rsin  = fminf(rsin,  gin  + wf);  sfin[j]  = rsin;
    rsout = fminf(rsout, gout + wf);  sfout[j] = rsout;
  }
  float zin = rsin, zout = rsout;
  for (int off = 1; off < 64; off <<= 1) {
    float yi = __shfl_down(zin, off);
    float yo = __shfl_down(zout, off);
    if (lane + off < 64) { zin = fminf(zin, yi); zout = fminf(zout, yo); }
  }
  float sein  = __shfl_down(zin, 1);  if (lane == 63) sein  = BIGF;
  float seout = __shfl_down(zout, 1); if (lane == 63) seout = BIGF;

  unsigned int outp[8];
  for (int j = 0; j < 8; ++j) {
    float wf = (float)(lane * 8 + j);
    float fin  = wf + fminf(pin[j],  ein);
    float fout = wf + fminf(pout[j], eout);
    float bin  = fminf(sfin[j],  sein)  - wf;
    float bout = fminf(sfout[j], seout) - wf;
    float g1i = fminf(fin,  bin);
    float g1o = fminf(fout, bout);
    unsigned int di = (g1i > 65534.f) ? 0xFFFFu : (unsigned int)(g1i + 0.5f);
    unsigned int dq = (g1o > 65534.f) ? 0xFFFFu : (unsigned int)(g1o + 0.5f);
    outp[j] = di | (dq << 16);
  }
  unsigned int* dst = packed + (size_t)row * HW + lane * 8;
  *(uint4*)dst       = make_uint4(outp[0], outp[1], outp[2], outp[3]);
  *(uint4*)(dst + 4) = make_uint4(outp[4], outp[5], outp[6], outp[7]);
}

// ---------------------------------------------------------------------------
// Kernel B: column pass. Block = 64 cols x 64 output rows; window +-32 halo
// (<=128 rows). LDS = ONE signed-squared f32 plane: per pixel exactly one of
// (dist_in, dist_out) is nonzero, so v = +d^2 if pixel in m else -d^2 encodes
// both classes. needed_c[k] = fmaxf(sgn*v[k], 0). Stride 65 -> 2 lanes/bank
// (conflict-free). Direct LDS reads, NO register arrays (no scratch spill).
// dk=1..8 unconditional (independent reads), exact guarded tail for dk>=9.
// ---------------------------------------------------------------------------
#define ICH 64
#define HALO 32
__global__ __launch_bounds__(256) void k_cols(const unsigned int* __restrict__ packed,
                                              float* __restrict__ sd,
                                              float* __restrict__ partials) {
  __shared__ float sq[128 * 65];          // 33280 B
  const int tid = threadIdx.x;
  const int wx = blockIdx.x;              // 0..7  w-tile
  const int iy = blockIdx.y;              // 0..7  i-chunk
  const int n  = blockIdx.z;
  const int I0 = iy * ICH;
  const int kb = max(0, I0 - HALO);
  const int ke = min(HH, I0 + ICH + HALO);
  const int sz = ke - kb;
  const int w0 = wx * 64;
  const unsigned int* src = packed + (size_t)n * NPIX + (size_t)kb * HW + w0;

  // stage: sz rows x 64 cols; uint4 load -> 4 scalar LDS writes (signed d^2)
  const int total4 = sz * 16;
  for (int p4 = tid; p4 < total4; p4 += 256) {
    int row = p4 >> 4;
    int c4  = (p4 & 15) << 2;
    uint4 v = *(const uint4*)(src + (size_t)row * HW + c4);
    unsigned int u[4] = {v.x, v.y, v.z, v.w};
#pragma unroll
    for (int e = 0; e < 4; ++e) {
      unsigned int lo = u[e] & 0xFFFFu;   // dist_in
      unsigned int hi = u[e] >> 16;       // dist_out
      unsigned int d  = lo | hi;          // exactly one is nonzero
      float dsq = (float)(d * d);         // <= 65535^2 < 2^32, exact enough (inf-like)
      sq[row * 65 + c4 + e] = (hi == 0u) ? dsq : -dsq;  // + if pixel in m
    }
  }
  __syncthreads();

  const int lane = tid & 63;
  const int wv   = tid >> 6;
  const int col  = lane;
  const int base = (I0 - kb) + wv * 16;   // this thread's first window row
  float lmax = -BIGF;

  for (int q = 0; q < 16; ++q) {
    const int li = base + q;
    const float own = sq[li * 65 + col];
    const bool  m   = own > 0.f;          // inside <=> dist_out == 0
    const float sgn = m ? 1.f : -1.f;
    float best = fabsf(own);
#pragma unroll
    for (int dk = 1; dk <= 8; ++dk) {     // unconditional, independent reads
      const float dkk = (float)(dk * dk);
      int k1 = li - dk, k2 = li + dk;
      float a = sgn * sq[max(k1, 0) * 65 + col];
      float b = sgn * sq[min(k2, sz - 1) * 65 + col];
      float ta = (k1 >= 0) ? fmaxf(a, 0.f) : SQINF;
      float tb = (k2 < sz) ? fmaxf(b, 0.f) : SQINF;
      best = fminf(best, ta + dkk);
      best = fminf(best, tb + dkk);
    }
    for (int dk = 9; dk < 128; ++dk) {    // rare exact tail
      float dkk = (float)(dk * dk);
      if (__all(dkk >= best)) break;
      int k1 = li - dk, k2 = li + dk;
      float a = sgn * sq[max(k1, 0) * 65 + col];
      float b = sgn * sq[min(k2, sz - 1) * 65 + col];
      float ta = (k1 >= 0) ? fmaxf(a, 0.f) : SQINF;
      float tb = (k2 < sz) ? fmaxf(b, 0.f) : SQINF;
      best = fminf(best, ta + dkk);
      best = fminf(best, tb + dkk);
    }
    const int i = I0 + wv * 16 + q;
    float s = m ? sqrtf(best) : -sqrtf(best);
    sd[(size_t)n * NPIX + (size_t)i * HW + w0 + col] = s;
    lmax = fmaxf(lmax, s);
  }
  for (int off = 32; off; off >>= 1) lmax = fmaxf(lmax, __shfl_xor(lmax, off));
  if (lane == 0) partials[((n * 8 + iy) * 8 + wx) * 4 + wv] = lmax;
}

// ---------------------------------------------------------------------------
// Kernel C: fused loss. Each block first reduces its image's 256 k_cols wave
// maxes (1 KB, L2) to get wsmax inline. Elementwise terms (8 px/thread, 10
// independent float4 loads). Binary targets: t in {0,1} => BCE needs ONE log:
// -log(t ? pc : 1-pc) (exactly equal, 0*log(x)=0 for finite log).
// Block partials stored to private slots (no contended atomics).
// ---------------------------------------------------------------------------
__global__ __launch_bounds__(256) void k_loss(const float* __restrict__ seg_p,
                                              const float* __restrict__ seg_t,
                                              const float* __restrict__ edge_p,
                                              const float* __restrict__ edge_t,
                                              const float* __restrict__ sd,
                                              const float* __restrict__ partials,
                                              float* __restrict__ partials2) {
  const int n = blockIdx.x >> 7;
  const int tid = threadIdx.x;
  const int wv = tid >> 6, ln = tid & 63;

  // inline wsmax reduce (256 values, one per thread)
  float v = partials[n * 256 + tid];
  for (int off = 32; off; off >>= 1) v = fmaxf(v, __shfl_xor(v, off));
  __shared__ float smax[4];
  if (ln == 0) smax[wv] = v;
  __syncthreads();
  const float mx = fmaxf(fmaxf(smax[0], smax[1]), fmaxf(smax[2], smax[3]));
  const float inv = (mx > 0.f) ? 1.f / (mx + 1e-6f) : 1.f;
  const float HI = 1.0f - 1e-7f;

  const size_t base = (size_t)n * NPIX + (size_t)(blockIdx.x & 127) * 2048
                    + (size_t)tid * 8;

  float a_bce = 0.f, a_pt = 0.f, a_ps = 0.f, a_ts = 0.f, a_ed = 0.f, a_bd = 0.f;
  for (int h = 0; h < 8; h += 4) {
    float4 p4  = *(const float4*)(seg_p  + base + h);
    float4 t4  = *(const float4*)(seg_t  + base + h);
    float4 ep4 = *(const float4*)(edge_p + base + h);
    float4 et4 = *(const float4*)(edge_t + base + h);
    float4 s4  = *(const float4*)(sd     + base + h);
    float pa[4]  = {p4.x, p4.y, p4.z, p4.w};
    float ta[4]  = {t4.x, t4.y, t4.z, t4.w};
    float epa[4] = {ep4.x, ep4.y, ep4.z, ep4.w};
    float eta[4] = {et4.x, et4.y, et4.z, et4.w};
    float sa[4]  = {s4.x, s4.y, s4.z, s4.w};
#pragma unroll
    for (int j = 0; j < 4; ++j) {
      float p = pa[j], t = ta[j];
      float pc = fminf(fmaxf(p, 1e-7f), HI);
      bool tm = t > 0.5f;
      a_bce -= __logf(tm ? pc : 1.f - pc);
      a_pt  += p * t;
      a_ps  += p;
      a_ts  += t;
      float ep = epa[j], et = eta[j];
      float ec = fminf(fmaxf(ep, 1e-7f), HI);
      bool em = et > 0.5f;
      a_ed -= __logf(em ? ec : 1.f - ec) * (em ? 0.9f : 0.1f);
      float sn = sa[j] * inv;
      sn = fminf(fmaxf(sn, -1.f), 1.f);
      a_bd += fabsf(p - t) * fabsf(sn);
    }
  }
  for (int off = 32; off; off >>= 1) {
    a_bce += __shfl_xor(a_bce, off);
    a_pt  += __shfl_xor(a_pt,  off);
    a_ps  += __shfl_xor(a_ps,  off);
    a_ts  += __shfl_xor(a_ts,  off);
    a_ed  += __shfl_xor(a_ed,  off);
    a_bd  += __shfl_xor(a_bd,  off);
  }
  __shared__ float red[4][6];
  if (ln == 0) {
    red[wv][0] = a_bce; red[wv][1] = a_pt; red[wv][2] = a_ps;
    red[wv][3] = a_ts;  red[wv][4] = a_ed; red[wv][5] = a_bd;
  }
  __syncthreads();
  if (tid == 0) {
    float* dst = partials2 + (size_t)blockIdx.x * 8;
    dst[0] = red[0][0] + red[1][0] + red[2][0] + red[3][0];
    dst[1] = red[0][1] + red[1][1] + red[2][1] + red[3][1];
    dst[2] = red[0][2] + red[1][2] + red[2][2] + red[3][2];
    dst[3] = red[0][3] + red[1][3] + red[2][3] + red[3][3];
    dst[4] = red[0][4] + red[1][4] + red[2][4] + red[3][4];
    dst[5] = red[0][5] + red[1][5] + red[2][5] + red[3][5];
  }
}

// ---------------------------------------------------------------------------
// Kernel D: final reduce of 1024 block-partials (32 KB, L2-resident) + scalar.
// ---------------------------------------------------------------------------
__global__ __launch_bounds__(256) void k_final(const float* __restrict__ partials2,
                                               float* __restrict__ out) {
  const int t = threadIdx.x;
  const int n = t >> 5;        // image 0..7
  const int l = t & 31;
  float s0 = 0.f, s1 = 0.f, s2 = 0.f, s3 = 0.f, s4 = 0.f, s5 = 0.f;
#pragma unroll
  for (int it = 0; it < 4; ++it) {
    const float* p = partials2 + (size_t)((n * 128) + l + it * 32) * 8;
    s0 += p[0]; s1 += p[1]; s2 += p[2];
    s3 += p[3]; s4 += p[4]; s5 += p[5];
  }
  for (int off = 16; off; off >>= 1) {
    s0 += __shfl_xor(s0, off); s1 += __shfl_xor(s1, off);
    s2 += __shfl_xor(s2, off); s3 += __shfl_xor(s3, off);
    s4 += __shfl_xor(s4, off); s5 += __shfl_xor(s5, off);
  }
  __shared__ float red[8][6];
  if (l == 0) {
    red[n][0] = s0; red[n][1] = s1; red[n][2] = s2;
    red[n][3] = s3; red[n][4] = s4; red[n][5] = s5;
  }
  __syncthreads();
  if (t == 0) {
    const float M = (float)NTOT;
    float bce = 0.f, ed = 0.f, bd = 0.f, dsum = 0.f;
    for (int nn = 0; nn < HN; ++nn) {
      bce += red[nn][0]; ed += red[nn][4]; bd += red[nn][5];
      float den = red[nn][2] + red[nn][3] + 1e-6f;
      dsum += 2.f * red[nn][1] / den;
    }
    float dice = 1.f - dsum / (float)HN;
    out[0] = bce / M + 0.5f * dice + 0.5f * (ed / M) + 0.2f * (bd / M);
  }
}

extern "C" void kernel_launch(void* const* d_in, const int* in_sizes, int n_in,
                              void* d_out, int out_size, void* d_ws, size_t ws_size,
                              hipStream_t stream) {
  const float* seg_p  = (const float*)d_in[0];
  const float* seg_t  = (const float*)d_in[1];
  const float* edge_p = (const float*)d_in[2];
  const float* edge_t = (const float*)d_in[3];
  float* out = (float*)d_out;

  char* ws = (char*)d_ws;
  unsigned int* packed = (unsigned int*)ws;                    // 8 MB: u16x2 row dists
  float* sd        = (float*)(ws + (size_t)NTOT * 4);          // 8 MB: signed distance
  float* partials  = (float*)(ws + (size_t)NTOT * 8);          // 8*256 floats (k_cols wave maxes)
  float* partials2 = partials + 8 * 256;                       // 1024*8 floats (k_loss partials)

  k_rows<<<dim3(HN * HH / 4), 256, 0, stream>>>(seg_t, packed);
  k_cols<<<dim3(8, 8, HN), 256, 0, stream>>>(packed, sd, partials);
  k_loss<<<dim3(HN * 128), 256, 0, stream>>>(seg_p, seg_t, edge_p, edge_t, sd, partials, partials2);
  k_final<<<1, 256, 0, stream>>>(partials2, out);
}

// Round 7
// 97.623 us; speedup vs baseline: 1.3740x; 1.0577x over previous
//
#include <hip/hip_runtime.h>
#include <math.h>

#define HN 8
#define HH 512
#define HW 512
#define NPIX (HH*HW)        // 262144 per image
#define NTOT (HN*NPIX)      // 2097152 total
#define INF1D 1.0e6f
#define BIGF 3.0e38f

// ---------------------------------------------------------------------------
// Kernel A: per-row 1D distance (along W) for both feature sets, packed u16x2.
// low16 = dist_in (EDT of ~m), high16 = dist_out (EDT of m).
// One wave per row; each lane owns 8 consecutive pixels.
// ---------------------------------------------------------------------------
__global__ __launch_bounds__(256) void k_rows(const float* __restrict__ gt,
                                              unsigned int* __restrict__ packed) {
  const int lane = threadIdx.x & 63;
  const int wv   = threadIdx.x >> 6;
  const int row  = blockIdx.x * 4 + wv;          // 0..4095 = n*512 + h
  const float* g = gt + (size_t)row * HW;

  float4 a0 = *(const float4*)(g + lane * 8);
  float4 a1 = *(const float4*)(g + lane * 8 + 4);
  float mv[8] = {a0.x, a0.y, a0.z, a0.w, a1.x, a1.y, a1.z, a1.w};

  float pin[8], pout[8], sfin[8], sfout[8];
  float rin = BIGF, rout = BIGF;
  for (int j = 0; j < 8; ++j) {
    float wf = (float)(lane * 8 + j);
    bool m = mv[j] > 0.5f;
    float gin  = m ? INF1D : 0.f;   // feature_in  = ~m
    float gout = m ? 0.f : INF1D;   // feature_out =  m
    rin  = fminf(rin,  gin  - wf);  pin[j]  = rin;
    rout = fminf(rout, gout - wf);  pout[j] = rout;
  }
  // exclusive wave prefix-min of lane totals
  float xin = rin, xout = rout;
  for (int off = 1; off < 64; off <<= 1) {
    float yi = __shfl_up(xin, off);
    float yo = __shfl_up(xout, off);
    if (lane >= off) { xin = fminf(xin, yi); xout = fminf(xout, yo); }
  }
  float ein  = __shfl_up(xin, 1);  if (lane == 0) ein  = BIGF;
  float eout = __shfl_up(xout, 1); if (lane == 0) eout = BIGF;

  float rsin = BIGF, rsout = BIGF;
  for (int j = 7; j >= 0; --j) {
    float wf = (float)(lane * 8 + j);
    bool m = mv[j] > 0.5f;
    float gin  = m ? INF1D : 0.f;
    float gout = m ? 0.f : INF1D;
    rsin  = fminf(rsin,  gin  + wf);  sfin[j]  = rsin;
    rsout = fminf(rsout, gout + wf);  sfout[j] = rsout;
  }
  float zin = rsin, zout = rsout;
  for (int off = 1; off < 64; off <<= 1) {
    float yi = __shfl_down(zin, off);
    float yo = __shfl_down(zout, off);
    if (lane + off < 64) { zin = fminf(zin, yi); zout = fminf(zout, yo); }
  }
  float sein  = __shfl_down(zin, 1);  if (lane == 63) sein  = BIGF;
  float seout = __shfl_down(zout, 1); if (lane == 63) seout = BIGF;

  unsigned int outp[8];
  for (int j = 0; j < 8; ++j) {
    float wf = (float)(lane * 8 + j);
    float fin  = wf + fminf(pin[j],  ein);
    float fout = wf + fminf(pout[j], eout);
    float bin  = fminf(sfin[j],  sein)  - wf;
    float bout = fminf(sfout[j], seout) - wf;
    float g1i = fminf(fin,  bin);
    float g1o = fminf(fout, bout);
    unsigned int di = (g1i > 65534.f) ? 0xFFFFu : (unsigned int)(g1i + 0.5f);
    unsigned int dq = (g1o > 65534.f) ? 0xFFFFu : (unsigned int)(g1o + 0.5f);
    outp[j] = di | (dq << 16);
  }
  unsigned int* dst = packed + (size_t)row * HW + lane * 8;
  *(uint4*)dst       = make_uint4(outp[0], outp[1], outp[2], outp[3]);
  *(uint4*)(dst + 4) = make_uint4(outp[4], outp[5], outp[6], outp[7]);
}

// ---------------------------------------------------------------------------
// Kernel B: column pass. Block = 64 cols x 64 output rows; window +-32 halo
// (<=128 rows). LDS = ONE signed-squared f32 plane (v = +d^2 inside m, -d^2
// outside; per pixel exactly one class distance is nonzero). Stride 68 words
// -> float4-aligned staging writes + conflict-free compute reads.
//
// Per thread: 16 consecutive rows of one column via a 17-register ROLLING
// window (all indices compile-time after unroll -> registers, no scratch).
// LDS reads: 17 init + 1/pixel (vs 17/pixel before). Clamped-index probes are
// exact: a clamped row's candidate d^2+dk^2 is dominated by that row's
// true-offset candidate probed at a smaller dk, so no OOB guards needed.
// dk=1..8 unconditional; guarded exact LDS tail for dk>=9 (rarely taken).
// ---------------------------------------------------------------------------
#define ICH 64
#define HALO 32
#define LSTR 68
__global__ __launch_bounds__(256) void k_cols(const unsigned int* __restrict__ packed,
                                              float* __restrict__ sd,
                                              float* __restrict__ partials) {
  __shared__ float sq[128 * LSTR];        // 34816 B
  const int tid = threadIdx.x;
  const int wx = blockIdx.x;              // 0..7  w-tile
  const int iy = blockIdx.y;              // 0..7  i-chunk
  const int n  = blockIdx.z;
  const int I0 = iy * ICH;
  const int kb = max(0, I0 - HALO);
  const int ke = min(HH, I0 + ICH + HALO);
  const int sz = ke - kb;
  const int w0 = wx * 64;
  const unsigned int* src = packed + (size_t)n * NPIX + (size_t)kb * HW + w0;

  // stage: sz rows x 64 cols; uint4 load -> one float4 LDS write (signed d^2)
  const int total4 = sz * 16;
  for (int p4 = tid; p4 < total4; p4 += 256) {
    int row = p4 >> 4;
    int c4  = (p4 & 15) << 2;
    uint4 v = *(const uint4*)(src + (size_t)row * HW + c4);
    unsigned int u[4] = {v.x, v.y, v.z, v.w};
    float f[4];
#pragma unroll
    for (int e = 0; e < 4; ++e) {
      unsigned int lo = u[e] & 0xFFFFu;   // dist_in
      unsigned int hi = u[e] >> 16;       // dist_out
      unsigned int d  = lo | hi;          // exactly one is nonzero
      float dsq = (float)(d * d);
      f[e] = (hi == 0u) ? dsq : -dsq;     // + if pixel in m
    }
    *(float4*)&sq[row * LSTR + c4] = make_float4(f[0], f[1], f[2], f[3]);
  }
  __syncthreads();

  const int lane = tid & 63;
  const int wv   = tid >> 6;
  const int col  = lane;
  const int base = (I0 - kb) + wv * 16;   // this thread's first output row (in window)
  float lmax = -BIGF;

  // rolling 17-register window over rows [base+q-8, base+q+8]
  float w[17];
#pragma unroll
  for (int t = 0; t < 17; ++t) {
    int rw = min(max(base - 8 + t, 0), sz - 1);
    w[t] = sq[rw * LSTR + col];
  }

#pragma unroll
  for (int q = 0; q < 16; ++q) {
    const float own = w[(8 + q) % 17];
    const bool  m   = own > 0.f;          // inside <=> dist_out == 0
    const float sgn = m ? 1.f : -1.f;
    float best = fabsf(own);
#pragma unroll
    for (int dk = 1; dk <= 8; ++dk) {
      const float dkk = (float)(dk * dk);
      float a = fmaxf(sgn * w[(8 + q - dk + 17) % 17], 0.f);
      float b = fmaxf(sgn * w[(8 + q + dk) % 17],      0.f);
      best = fminf(best, a + dkk);
      best = fminf(best, b + dkk);
    }
    const int li = base + q;
    for (int dk = 9; dk < 128; ++dk) {    // rare exact tail
      float dkk = (float)(dk * dk);
      if (__all(dkk >= best)) break;
      float a = fmaxf(sgn * sq[max(li - dk, 0) * LSTR + col], 0.f);
      float b = fmaxf(sgn * sq[min(li + dk, sz - 1) * LSTR + col], 0.f);
      best = fminf(best, a + dkk);
      best = fminf(best, b + dkk);
    }
    const int i = I0 + wv * 16 + q;
    float s = m ? sqrtf(best) : -sqrtf(best);
    sd[(size_t)n * NPIX + (size_t)i * HW + w0 + col] = s;
    lmax = fmaxf(lmax, s);
    // slide: bring in row base+q+9 (overwrites row base+q-8, slot q%17)
    if (q < 15) {
      int rw = min(base + q + 9, sz - 1);
      w[q % 17] = sq[rw * LSTR + col];
    }
  }
  for (int off = 32; off; off >>= 1) lmax = fmaxf(lmax, __shfl_xor(lmax, off));
  if (lane == 0) partials[((n * 8 + iy) * 8 + wx) * 4 + wv] = lmax;
}

// ---------------------------------------------------------------------------
// Kernel C: fused loss. Each block first reduces its image's 256 k_cols wave
// maxes (1 KB, L2) to get wsmax inline. Elementwise terms (8 px/thread, 10
// independent float4 loads). Binary targets: t in {0,1} => BCE needs ONE log:
// -log(t ? pc : 1-pc) (exactly equal, 0*log(x)=0 for finite log).
// Block partials stored to private slots (no contended atomics).
// ---------------------------------------------------------------------------
__global__ __launch_bounds__(256) void k_loss(const float* __restrict__ seg_p,
                                              const float* __restrict__ seg_t,
                                              const float* __restrict__ edge_p,
                                              const float* __restrict__ edge_t,
                                              const float* __restrict__ sd,
                                              const float* __restrict__ partials,
                                              float* __restrict__ partials2) {
  const int n = blockIdx.x >> 7;
  const int tid = threadIdx.x;
  const int wv = tid >> 6, ln = tid & 63;

  // inline wsmax reduce (256 values, one per thread)
  float v = partials[n * 256 + tid];
  for (int off = 32; off; off >>= 1) v = fmaxf(v, __shfl_xor(v, off));
  __shared__ float smax[4];
  if (ln == 0) smax[wv] = v;
  __syncthreads();
  const float mx = fmaxf(fmaxf(smax[0], smax[1]), fmaxf(smax[2], smax[3]));
  const float inv = (mx > 0.f) ? 1.f / (mx + 1e-6f) : 1.f;
  const float HI = 1.0f - 1e-7f;

  const size_t base = (size_t)n * NPIX + (size_t)(blockIdx.x & 127) * 2048
                    + (size_t)tid * 8;

  float a_bce = 0.f, a_pt = 0.f, a_ps = 0.f, a_ts = 0.f, a_ed = 0.f, a_bd = 0.f;
  for (int h = 0; h < 8; h += 4) {
    float4 p4  = *(const float4*)(seg_p  + base + h);
    float4 t4  = *(const float4*)(seg_t  + base + h);
    float4 ep4 = *(const float4*)(edge_p + base + h);
    float4 et4 = *(const float4*)(edge_t + base + h);
    float4 s4  = *(const float4*)(sd     + base + h);
    float pa[4]  = {p4.x, p4.y, p4.z, p4.w};
    float ta[4]  = {t4.x, t4.y, t4.z, t4.w};
    float epa[4] = {ep4.x, ep4.y, ep4.z, ep4.w};
    float eta[4] = {et4.x, et4.y, et4.z, et4.w};
    float sa[4]  = {s4.x, s4.y, s4.z, s4.w};
#pragma unroll
    for (int j = 0; j < 4; ++j) {
      float p = pa[j], t = ta[j];
      float pc = fminf(fmaxf(p, 1e-7f), HI);
      bool tm = t > 0.5f;
      a_bce -= __logf(tm ? pc : 1.f - pc);
      a_pt  += p * t;
      a_ps  += p;
      a_ts  += t;
      float ep = epa[j], et = eta[j];
      float ec = fminf(fmaxf(ep, 1e-7f), HI);
      bool em = et > 0.5f;
      a_ed -= __logf(em ? ec : 1.f - ec) * (em ? 0.9f : 0.1f);
      float sn = sa[j] * inv;
      sn = fminf(fmaxf(sn, -1.f), 1.f);
      a_bd += fabsf(p - t) * fabsf(sn);
    }
  }
  for (int off = 32; off; off >>= 1) {
    a_bce += __shfl_xor(a_bce, off);
    a_pt  += __shfl_xor(a_pt,  off);
    a_ps  += __shfl_xor(a_ps,  off);
    a_ts  += __shfl_xor(a_ts,  off);
    a_ed  += __shfl_xor(a_ed,  off);
    a_bd  += __shfl_xor(a_bd,  off);
  }
  __shared__ float red[4][6];
  if (ln == 0) {
    red[wv][0] = a_bce; red[wv][1] = a_pt; red[wv][2] = a_ps;
    red[wv][3] = a_ts;  red[wv][4] = a_ed; red[wv][5] = a_bd;
  }
  __syncthreads();
  if (tid == 0) {
    float* dst = partials2 + (size_t)blockIdx.x * 8;
    dst[0] = red[0][0] + red[1][0] + red[2][0] + red[3][0];
    dst[1] = red[0][1] + red[1][1] + red[2][1] + red[3][1];
    dst[2] = red[0][2] + red[1][2] + red[2][2] + red[3][2];
    dst[3] = red[0][3] + red[1][3] + red[2][3] + red[3][3];
    dst[4] = red[0][4] + red[1][4] + red[2][4] + red[3][4];
    dst[5] = red[0][5] + red[1][5] + red[2][5] + red[3][5];
  }
}

// ---------------------------------------------------------------------------
// Kernel D: final reduce of 1024 block-partials (32 KB, L2-resident) + scalar.
// ---------------------------------------------------------------------------
__global__ __launch_bounds__(256) void k_final(const float* __restrict__ partials2,
                                               float* __restrict__ out) {
  const int t = threadIdx.x;
  const int n = t >> 5;        // image 0..7
  const int l = t & 31;
  float s0 = 0.f, s1 = 0.f, s2 = 0.f, s3 = 0.f, s4 = 0.f, s5 = 0.f;
#pragma unroll
  for (int it = 0; it < 4; ++it) {
    const float* p = partials2 + (size_t)((n * 128) + l + it * 32) * 8;
    s0 += p[0]; s1 += p[1]; s2 += p[2];
    s3 += p[3]; s4 += p[4]; s5 += p[5];
  }
  for (int off = 16; off; off >>= 1) {
    s0 += __shfl_xor(s0, off); s1 += __shfl_xor(s1, off);
    s2 += __shfl_xor(s2, off); s3 += __shfl_xor(s3, off);
    s4 += __shfl_xor(s4, off); s5 += __shfl_xor(s5, off);
  }
  __shared__ float red[8][6];
  if (l == 0) {
    red[n][0] = s0; red[n][1] = s1; red[n][2] = s2;
    red[n][3] = s3; red[n][4] = s4; red[n][5] = s5;
  }
  __syncthreads();
  if (t == 0) {
    const float M = (float)NTOT;
    float bce = 0.f, ed = 0.f, bd = 0.f, dsum = 0.f;
    for (int nn = 0; nn < HN; ++nn) {
      bce += red[nn][0]; ed += red[nn][4]; bd += red[nn][5];
      float den = red[nn][2] + red[nn][3] + 1e-6f;
      dsum += 2.f * red[nn][1] / den;
    }
    float dice = 1.f - dsum / (float)HN;
    out[0] = bce / M + 0.5f * dice + 0.5f * (ed / M) + 0.2f * (bd / M);
  }
}

extern "C" void kernel_launch(void* const* d_in, const int* in_sizes, int n_in,
                              void* d_out, int out_size, void* d_ws, size_t ws_size,
                              hipStream_t stream) {
  const float* seg_p  = (const float*)d_in[0];
  const float* seg_t  = (const float*)d_in[1];
  const float* edge_p = (const float*)d_in[2];
  const float* edge_t = (const float*)d_in[3];
  float* out = (float*)d_out;

  char* ws = (char*)d_ws;
  unsigned int* packed = (unsigned int*)ws;                    // 8 MB: u16x2 row dists
  float* sd        = (float*)(ws + (size_t)NTOT * 4);          // 8 MB: signed distance
  float* partials  = (float*)(ws + (size_t)NTOT * 8);          // 8*256 floats (k_cols wave maxes)
  float* partials2 = partials + 8 * 256;                       // 1024*8 floats (k_loss partials)

  k_rows<<<dim3(HN * HH / 4), 256, 0, stream>>>(seg_t, packed);
  k_cols<<<dim3(8, 8, HN), 256, 0, stream>>>(packed, sd, partials);
  k_loss<<<dim3(HN * 128), 256, 0, stream>>>(seg_p, seg_t, edge_p, edge_t, sd, partials, partials2);
  k_final<<<1, 256, 0, stream>>>(partials2, out);
}

// Round 8
// 95.531 us; speedup vs baseline: 1.4040x; 1.0219x over previous
//
#include <hip/hip_runtime.h>
#include <math.h>

#define HN 8
#define HH 512
#define HW 512
#define NPIX (HH*HW)        // 262144 per image
#define NTOT (HN*NPIX)      // 2097152 total
#define INF1D 1.0e6f
#define BIGF 3.0e38f

// async global->LDS, 16B per lane (dest must be wave-uniform base + lane*16)
__device__ __forceinline__ void g2l16(const float* g, float* l) {
  __builtin_amdgcn_global_load_lds(
      (const __attribute__((address_space(1))) void*)g,
      (__attribute__((address_space(3))) void*)l, 16, 0, 0);
}

// ---------------------------------------------------------------------------
// Kernel A: per-row 1D distance (along W) for both feature sets, emitted as
// SIGNED SQUARED f32: v = +din^2 if pixel in m (dout==0), else -dout^2.
// Exactly one of (din,dout) is nonzero per pixel. Sentinel rows give 1e12.
// One wave per row; each lane owns 8 consecutive pixels.
// ---------------------------------------------------------------------------
__global__ __launch_bounds__(256) void k_rows(const float* __restrict__ gt,
                                              float* __restrict__ sqg) {
  const int lane = threadIdx.x & 63;
  const int wv   = threadIdx.x >> 6;
  const int row  = blockIdx.x * 4 + wv;          // 0..4095 = n*512 + h
  const float* g = gt + (size_t)row * HW;

  float4 a0 = *(const float4*)(g + lane * 8);
  float4 a1 = *(const float4*)(g + lane * 8 + 4);
  float mv[8] = {a0.x, a0.y, a0.z, a0.w, a1.x, a1.y, a1.z, a1.w};

  float pin[8], pout[8], sfin[8], sfout[8];
  float rin = BIGF, rout = BIGF;
  for (int j = 0; j < 8; ++j) {
    float wf = (float)(lane * 8 + j);
    bool m = mv[j] > 0.5f;
    float gin  = m ? INF1D : 0.f;   // feature_in  = ~m
    float gout = m ? 0.f : INF1D;   // feature_out =  m
    rin  = fminf(rin,  gin  - wf);  pin[j]  = rin;
    rout = fminf(rout, gout - wf);  pout[j] = rout;
  }
  // exclusive wave prefix-min of lane totals
  float xin = rin, xout = rout;
  for (int off = 1; off < 64; off <<= 1) {
    float yi = __shfl_up(xin, off);
    float yo = __shfl_up(xout, off);
    if (lane >= off) { xin = fminf(xin, yi); xout = fminf(xout, yo); }
  }
  float ein  = __shfl_up(xin, 1);  if (lane == 0) ein  = BIGF;
  float eout = __shfl_up(xout, 1); if (lane == 0) eout = BIGF;

  float rsin = BIGF, rsout = BIGF;
  for (int j = 7; j >= 0; --j) {
    float wf = (float)(lane * 8 + j);
    bool m = mv[j] > 0.5f;
    float gin  = m ? INF1D : 0.f;
    float gout = m ? 0.f : INF1D;
    rsin  = fminf(rsin,  gin  + wf);  sfin[j]  = rsin;
    rsout = fminf(rsout, gout + wf);  sfout[j] = rsout;
  }
  float zin = rsin, zout = rsout;
  for (int off = 1; off < 64; off <<= 1) {
    float yi = __shfl_down(zin, off);
    float yo = __shfl_down(zout, off);
    if (lane + off < 64) { zin = fminf(zin, yi); zout = fminf(zout, yo); }
  }
  float sein  = __shfl_down(zin, 1);  if (lane == 63) sein  = BIGF;
  float seout = __shfl_down(zout, 1); if (lane == 63) seout = BIGF;

  float outp[8];
  for (int j = 0; j < 8; ++j) {
    float wf = (float)(lane * 8 + j);
    float fin  = wf + fminf(pin[j],  ein);
    float fout = wf + fminf(pout[j], eout);
    float bin  = fminf(sfin[j],  sein)  - wf;
    float bout = fminf(sfout[j], seout) - wf;
    float g1i = fminf(fin,  bin);    // dist_in  (0 if pixel outside m)
    float g1o = fminf(fout, bout);   // dist_out (0 if pixel inside  m)
    outp[j] = (g1o == 0.f) ? g1i * g1i : -(g1o * g1o);
  }
  float* dst = sqg + (size_t)row * HW + lane * 8;
  *(float4*)dst       = make_float4(outp[0], outp[1], outp[2], outp[3]);
  *(float4*)(dst + 4) = make_float4(outp[4], outp[5], outp[6], outp[7]);
}

// ---------------------------------------------------------------------------
// Kernel B: column pass. Block = 64 cols x 64 output rows; window +-32 halo
// (<=128 rows). LDS = signed-squared f32 plane, stride 64 (a wave's compute
// read is one full 64-word row -> 2 lanes/bank, conflict-free). Staging is a
// pure global_load_lds DMA (dest offset = 16*p4 = wave-uniform + lane*16).
// Per thread: 16 rows of one column via a 17-register rolling window (all
// indices compile-time -> registers, no scratch). Probe math uses the exact
// identity fmax(sgn*v,0)+dk^2 == fmax(fma(sgn,v,dk^2), dk^2). Clamped-index
// probes are exact (dominated by the true-offset candidate at smaller dk).
// dk=1..8 unconditional; guarded exact LDS tail for dk>=9 (rarely taken).
// ---------------------------------------------------------------------------
#define ICH 64
#define HALO 32
__global__ __launch_bounds__(256) void k_cols(const float* __restrict__ sqg,
                                              float* __restrict__ sd,
                                              float* __restrict__ partials) {
  __shared__ float sq[128 * 64];          // 32 KB
  const int tid = threadIdx.x;
  const int wx = blockIdx.x;              // 0..7  w-tile
  const int iy = blockIdx.y;              // 0..7  i-chunk
  const int n  = blockIdx.z;
  const int I0 = iy * ICH;
  const int kb = max(0, I0 - HALO);
  const int ke = min(HH, I0 + ICH + HALO);
  const int sz = ke - kb;                 // 96 or 128 (multiple of 32)
  const int w0 = wx * 64;
  const float* src = sqg + (size_t)n * NPIX + (size_t)kb * HW + w0;

  // stage: sz rows x 64 cols as pure 16B DMA; dest word = 4*p4 (linear)
  const int total4 = sz * 16;             // multiple of 256
  for (int p4 = tid; p4 < total4; p4 += 256) {
    int row = p4 >> 4;
    int c4  = (p4 & 15) << 2;
    g2l16(src + (size_t)row * HW + c4, &sq[p4 << 2]);
  }
  __syncthreads();

  const int lane = tid & 63;
  const int wv   = tid >> 6;
  const int col  = lane;
  const int base = (I0 - kb) + wv * 16;   // this thread's first output row (in window)
  float lmax = -BIGF;

  // rolling 17-register window over rows [base+q-8, base+q+8]
  float w[17];
#pragma unroll
  for (int t = 0; t < 17; ++t) {
    int rw = min(max(base - 8 + t, 0), sz - 1);
    w[t] = sq[rw * 64 + col];
  }

#pragma unroll
  for (int q = 0; q < 16; ++q) {
    const float own = w[(8 + q) % 17];
    const bool  m   = own > 0.f;          // inside <=> dist_out == 0
    const float sgn = m ? 1.f : -1.f;
    float best = fabsf(own);
#pragma unroll
    for (int dk = 1; dk <= 8; ++dk) {
      const float dkk = (float)(dk * dk);
      float a = fmaxf(__builtin_fmaf(sgn, w[(8 + q - dk + 17) % 17], dkk), dkk);
      float b = fmaxf(__builtin_fmaf(sgn, w[(8 + q + dk) % 17],      dkk), dkk);
      best = fminf(best, a);
      best = fminf(best, b);
    }
    const int li = base + q;
    for (int dk = 9; dk < 128; ++dk) {    // rare exact tail
      float dkk = (float)(dk * dk);
      if (__all(dkk >= best)) break;
      float a = fmaxf(__builtin_fmaf(sgn, sq[max(li - dk, 0) * 64 + col], dkk), dkk);
      float b = fmaxf(__builtin_fmaf(sgn, sq[min(li + dk, sz - 1) * 64 + col], dkk), dkk);
      best = fminf(best, a);
      best = fminf(best, b);
    }
    const int i = I0 + wv * 16 + q;
    float s = m ? sqrtf(best) : -sqrtf(best);
    sd[(size_t)n * NPIX + (size_t)i * HW + w0 + col] = s;
    lmax = fmaxf(lmax, s);
    // slide: bring in row base+q+9 (overwrites row base+q-8, slot q%17)
    if (q < 15) {
      int rw = min(base + q + 9, sz - 1);
      w[q % 17] = sq[rw * 64 + col];
    }
  }
  for (int off = 32; off; off >>= 1) lmax = fmaxf(lmax, __shfl_xor(lmax, off));
  if (lane == 0) partials[((n * 8 + iy) * 8 + wx) * 4 + wv] = lmax;
}

// ---------------------------------------------------------------------------
// Kernel C: fused loss. Each block first reduces its image's 256 k_cols wave
// maxes (1 KB, L2) to get wsmax inline. Elementwise terms (8 px/thread, 10
// independent float4 loads). Binary targets: t in {0,1} => BCE needs ONE log:
// -log(t ? pc : 1-pc) (exactly equal, 0*log(x)=0 for finite log).
// Block partials stored to private slots (no contended atomics).
// ---------------------------------------------------------------------------
__global__ __launch_bounds__(256) void k_loss(const float* __restrict__ seg_p,
                                              const float* __restrict__ seg_t,
                                              const float* __restrict__ edge_p,
                                              const float* __restrict__ edge_t,
                                              const float* __restrict__ sd,
                                              const float* __restrict__ partials,
                                              float* __restrict__ partials2) {
  const int n = blockIdx.x >> 7;
  const int tid = threadIdx.x;
  const int wv = tid >> 6, ln = tid & 63;

  // inline wsmax reduce (256 values, one per thread)
  float v = partials[n * 256 + tid];
  for (int off = 32; off; off >>= 1) v = fmaxf(v, __shfl_xor(v, off));
  __shared__ float smax[4];
  if (ln == 0) smax[wv] = v;
  __syncthreads();
  const float mx = fmaxf(fmaxf(smax[0], smax[1]), fmaxf(smax[2], smax[3]));
  const float inv = (mx > 0.f) ? 1.f / (mx + 1e-6f) : 1.f;
  const float HI = 1.0f - 1e-7f;

  const size_t base = (size_t)n * NPIX + (size_t)(blockIdx.x & 127) * 2048
                    + (size_t)tid * 8;

  float a_bce = 0.f, a_pt = 0.f, a_ps = 0.f, a_ts = 0.f, a_ed = 0.f, a_bd = 0.f;
  for (int h = 0; h < 8; h += 4) {
    float4 p4  = *(const float4*)(seg_p  + base + h);
    float4 t4  = *(const float4*)(seg_t  + base + h);
    float4 ep4 = *(const float4*)(edge_p + base + h);
    float4 et4 = *(const float4*)(edge_t + base + h);
    float4 s4  = *(const float4*)(sd     + base + h);
    float pa[4]  = {p4.x, p4.y, p4.z, p4.w};
    float ta[4]  = {t4.x, t4.y, t4.z, t4.w};
    float epa[4] = {ep4.x, ep4.y, ep4.z, ep4.w};
    float eta[4] = {et4.x, et4.y, et4.z, et4.w};
    float sa[4]  = {s4.x, s4.y, s4.z, s4.w};
#pragma unroll
    for (int j = 0; j < 4; ++j) {
      float p = pa[j], t = ta[j];
      float pc = fminf(fmaxf(p, 1e-7f), HI);
      bool tm = t > 0.5f;
      a_bce -= __logf(tm ? pc : 1.f - pc);
      a_pt  += p * t;
      a_ps  += p;
      a_ts  += t;
      float ep = epa[j], et = eta[j];
      float ec = fminf(fmaxf(ep, 1e-7f), HI);
      bool em = et > 0.5f;
      a_ed -= __logf(em ? ec : 1.f - ec) * (em ? 0.9f : 0.1f);
      float sn = sa[j] * inv;
      sn = fminf(fmaxf(sn, -1.f), 1.f);
      a_bd += fabsf(p - t) * fabsf(sn);
    }
  }
  for (int off = 32; off; off >>= 1) {
    a_bce += __shfl_xor(a_bce, off);
    a_pt  += __shfl_xor(a_pt,  off);
    a_ps  += __shfl_xor(a_ps,  off);
    a_ts  += __shfl_xor(a_ts,  off);
    a_ed  += __shfl_xor(a_ed,  off);
    a_bd  += __shfl_xor(a_bd,  off);
  }
  __shared__ float red[4][6];
  if (ln == 0) {
    red[wv][0] = a_bce; red[wv][1] = a_pt; red[wv][2] = a_ps;
    red[wv][3] = a_ts;  red[wv][4] = a_ed; red[wv][5] = a_bd;
  }
  __syncthreads();
  if (tid == 0) {
    float* dst = partials2 + (size_t)blockIdx.x * 8;
    dst[0] = red[0][0] + red[1][0] + red[2][0] + red[3][0];
    dst[1] = red[0][1] + red[1][1] + red[2][1] + red[3][1];
    dst[2] = red[0][2] + red[1][2] + red[2][2] + red[3][2];
    dst[3] = red[0][3] + red[1][3] + red[2][3] + red[3][3];
    dst[4] = red[0][4] + red[1][4] + red[2][4] + red[3][4];
    dst[5] = red[0][5] + red[1][5] + red[2][5] + red[3][5];
  }
}

// ---------------------------------------------------------------------------
// Kernel D: final reduce of 1024 block-partials (32 KB, L2-resident) + scalar.
// ---------------------------------------------------------------------------
__global__ __launch_bounds__(256) void k_final(const float* __restrict__ partials2,
                                               float* __restrict__ out) {
  const int t = threadIdx.x;
  const int n = t >> 5;        // image 0..7
  const int l = t & 31;
  float s0 = 0.f, s1 = 0.f, s2 = 0.f, s3 = 0.f, s4 = 0.f, s5 = 0.f;
#pragma unroll
  for (int it = 0; it < 4; ++it) {
    const float* p = partials2 + (size_t)((n * 128) + l + it * 32) * 8;
    s0 += p[0]; s1 += p[1]; s2 += p[2];
    s3 += p[3]; s4 += p[4]; s5 += p[5];
  }
  for (int off = 16; off; off >>= 1) {
    s0 += __shfl_xor(s0, off); s1 += __shfl_xor(s1, off);
    s2 += __shfl_xor(s2, off); s3 += __shfl_xor(s3, off);
    s4 += __shfl_xor(s4, off); s5 += __shfl_xor(s5, off);
  }
  __shared__ float red[8][6];
  if (l == 0) {
    red[n][0] = s0; red[n][1] = s1; red[n][2] = s2;
    red[n][3] = s3; red[n][4] = s4; red[n][5] = s5;
  }
  __syncthreads();
  if (t == 0) {
    const float M = (float)NTOT;
    float bce = 0.f, ed = 0.f, bd = 0.f, dsum = 0.f;
    for (int nn = 0; nn < HN; ++nn) {
      bce += red[nn][0]; ed += red[nn][4]; bd += red[nn][5];
      float den = red[nn][2] + red[nn][3] + 1e-6f;
      dsum += 2.f * red[nn][1] / den;
    }
    float dice = 1.f - dsum / (float)HN;
    out[0] = bce / M + 0.5f * dice + 0.5f * (ed / M) + 0.2f * (bd / M);
  }
}

extern "C" void kernel_launch(void* const* d_in, const int* in_sizes, int n_in,
                              void* d_out, int out_size, void* d_ws, size_t ws_size,
                              hipStream_t stream) {
  const float* seg_p  = (const float*)d_in[0];
  const float* seg_t  = (const float*)d_in[1];
  const float* edge_p = (const float*)d_in[2];
  const float* edge_t = (const float*)d_in[3];
  float* out = (float*)d_out;

  char* ws = (char*)d_ws;
  float* sqg       = (float*)ws;                               // 8 MB: signed d^2 row dists
  float* sd        = (float*)(ws + (size_t)NTOT * 4);          // 8 MB: signed distance
  float* partials  = (float*)(ws + (size_t)NTOT * 8);          // 8*256 floats (k_cols wave maxes)
  float* partials2 = partials + 8 * 256;                       // 1024*8 floats (k_loss partials)

  k_rows<<<dim3(HN * HH / 4), 256, 0, stream>>>(seg_t, sqg);
  k_cols<<<dim3(8, 8, HN), 256, 0, stream>>>(sqg, sd, partials);
  k_loss<<<dim3(HN * 128), 256, 0, stream>>>(seg_p, seg_t, edge_p, edge_t, sd, partials, partials2);
  k_final<<<1, 256, 0, stream>>>(partials2, out);
}